// Round 21
// baseline (213.737 us; speedup 1.0000x reference)
//
#include <hip/hip_runtime.h>
#include <hip/hip_bf16.h>
#include <stdint.h>

#define D_MODEL 1024
#define TOKENS  2048
#define HEADS   16
#define HDIM    64
#define NQKV    3072      // 3*D_MODEL
#define MROWS   4096      // BATCH*TOKENS
#define SCALE   0.18033688011112042f   // 0.125 * log2(e)

typedef __attribute__((ext_vector_type(4)))  float f32x4;
typedef __attribute__((ext_vector_type(16))) float f32x16;
typedef __attribute__((ext_vector_type(8)))  short bf16x8;

__device__ __forceinline__ unsigned short f2bf(float f) {
  union { float f; unsigned u; } v; v.f = f;
  unsigned u = v.u + 0x7FFFu + ((v.u >> 16) & 1u);   // RNE
  return (unsigned short)(u >> 16);
}
__device__ __forceinline__ float bf2f(unsigned short b) {
  union { unsigned u; float f; } v; v.u = ((unsigned)b) << 16;
  return v.f;
}
__device__ __forceinline__ unsigned cvt_pk_bf16(float lo, float hi) {
  unsigned r;
  asm("v_cvt_pk_bf16_f32 %0, %1, %2" : "=v"(r) : "v"(lo), "v"(hi));
  return r;
}
__device__ __forceinline__ float xchg32(float v) {
  return __shfl_xor(v, 32);
}
__device__ __forceinline__ bf16x8 pfrag8(const float* g) {
  union { uint4 u; bf16x8 v; } r;
  r.u.x = cvt_pk_bf16(g[0], g[1]);
  r.u.y = cvt_pk_bf16(g[2], g[3]);
  r.u.z = cvt_pk_bf16(g[4], g[5]);
  r.u.w = cvt_pk_bf16(g[6], g[7]);
  return r.v;
}
__device__ __forceinline__ float max32t(const f32x16& a, const f32x16& b) {
  float t[16];
#pragma unroll
  for (int r = 0; r < 16; ++r) t[r] = fmaxf(a[r], b[r]);
#pragma unroll
  for (int s = 8; s > 0; s >>= 1)
#pragma unroll
    for (int r = 0; r < s; ++r) t[r] = fmaxf(t[r], t[r + s]);
  return t[0];
}
__device__ __forceinline__ float sum32t(const float* a, const float* b) {
  float t[16];
#pragma unroll
  for (int r = 0; r < 16; ++r) t[r] = a[r] + b[r];
#pragma unroll
  for (int s = 8; s > 0; s >>= 1)
#pragma unroll
    for (int r = 0; r < s; ++r) t[r] = t[r] + t[r + s];
  return t[0];
}

#define GLOAD16(g, l)                                                          \
  __builtin_amdgcn_global_load_lds(                                            \
      (const __attribute__((address_space(1))) unsigned int*)(g),              \
      (__attribute__((address_space(3))) unsigned int*)(l), 16, 0, 0)

// ---------------------------------------------------------------------------
// fp32 -> bf16 convert pass (X then W, contiguous).
// ---------------------------------------------------------------------------
__global__ __launch_bounds__(256) void cvt_bf16(const float* __restrict__ X,
                                                const float* __restrict__ W,
                                                unsigned short* __restrict__ Xb,
                                                unsigned short* __restrict__ Wb) {
  const size_t NX = (size_t)MROWS * D_MODEL;
  size_t i = ((size_t)blockIdx.x * 256 + threadIdx.x) * 8;
  const float* src; unsigned short* dst; size_t off;
  if (i < NX) { src = X; dst = Xb; off = i; }
  else        { src = W; dst = Wb; off = i - NX; }
  float4 a = ((const float4*)(src + off))[0];
  float4 b = ((const float4*)(src + off))[1];
  union { unsigned short s[8]; uint4 v; } u;
  u.s[0] = f2bf(a.x); u.s[1] = f2bf(a.y); u.s[2] = f2bf(a.z); u.s[3] = f2bf(a.w);
  u.s[4] = f2bf(b.x); u.s[5] = f2bf(b.y); u.s[6] = f2bf(b.z); u.s[7] = f2bf(b.w);
  *(uint4*)(dst + off) = u.v;
}

// ---------------------------------------------------------------------------
// 8-phase 256x256 GEMM (round-17 verified: full swizzle + A-frag reuse).
// ---------------------------------------------------------------------------
__global__ __launch_bounds__(512, 1) void gemm8(const unsigned short* __restrict__ A,
                                                const unsigned short* __restrict__ B,
                                                unsigned short* __restrict__ C) {
  __shared__ unsigned short sA[2][2][128][64];
  __shared__ unsigned short sB[2][2][128][64];

  const int tid  = threadIdx.x;
  const int lane = tid & 63;
  const int wave = tid >> 6;
  const int wr   = wave >> 2;
  const int wc   = wave & 3;
  const int l15  = lane & 15;
  const int lg   = lane >> 4;

  const int bm = blockIdx.x;
  const int bn = blockIdx.y;

  f32x4 acc[8][4];
#pragma unroll
  for (int i = 0; i < 8; ++i)
#pragma unroll
    for (int j = 0; j < 4; ++j)
#pragma unroll
      for (int r = 0; r < 4; ++r) acc[i][j][r] = 0.f;

  const int srow = tid >> 3;
  const int scb  = (tid & 7) * 16;
  const int ssce = (scb ^ ((srow & 7) << 4)) >> 1;

  const unsigned short* Ag = A + (size_t)(bm * 256) * D_MODEL;
  const unsigned short* Bg = B + (size_t)(bn * 256) * D_MODEL;

#define STG_A(buf, hf, t)                                                      \
  { GLOAD16(Ag + (size_t)((hf) * 128 + srow) * D_MODEL + (t) * 64 + ssce,      \
            (char*)&sA[buf][hf][0][0] + srow * 128 + scb);                     \
    GLOAD16(Ag + (size_t)((hf) * 128 + 64 + srow) * D_MODEL + (t) * 64 + ssce, \
            (char*)&sA[buf][hf][0][0] + 8192 + srow * 128 + scb); }
#define STG_B(buf, hf, t)                                                      \
  { GLOAD16(Bg + (size_t)((hf) * 128 + srow) * D_MODEL + (t) * 64 + ssce,      \
            (char*)&sB[buf][hf][0][0] + srow * 128 + scb);                     \
    GLOAD16(Bg + (size_t)((hf) * 128 + 64 + srow) * D_MODEL + (t) * 64 + ssce, \
            (char*)&sB[buf][hf][0][0] + 8192 + srow * 128 + scb); }

  const char* aBse[2] = { (const char*)&sA[0][wr][0][0], (const char*)&sA[1][wr][0][0] };
  const char* bBse[2] = { (const char*)&sB[0][wc >> 1][0][0], (const char*)&sB[1][wc >> 1][0][0] };
  const int swzl = (l15 & 7) << 4;
  const int cbs0 = (lg * 16) ^ swzl;
  const int cbs1 = (64 + lg * 16) ^ swzl;
  const int arow = l15 * 128;
  const int brow = ((wc & 1) * 64 + l15) * 128;

  bf16x8 aF[4][2];

#define DO_PHASE(qm, qn, buf, LD_A, STAGE_STMT, DO_VM)                         \
  {                                                                            \
    if (LD_A) {                                                                \
      _Pragma("unroll")                                                        \
      for (int i = 0; i < 4; ++i) {                                            \
        aF[i][0] = *(const bf16x8*)(aBse[buf] + ((qm)*4 + i) * 2048 + arow + cbs0); \
        aF[i][1] = *(const bf16x8*)(aBse[buf] + ((qm)*4 + i) * 2048 + arow + cbs1); \
      }                                                                        \
    }                                                                          \
    bf16x8 b_[2][2];                                                           \
    _Pragma("unroll")                                                          \
    for (int n = 0; n < 2; ++n) {                                              \
      b_[n][0] = *(const bf16x8*)(bBse[buf] + ((qn)*2 + n) * 2048 + brow + cbs0); \
      b_[n][1] = *(const bf16x8*)(bBse[buf] + ((qn)*2 + n) * 2048 + brow + cbs1); \
    }                                                                          \
    STAGE_STMT;                                                                \
    if (DO_VM) asm volatile("s_waitcnt vmcnt(2)" ::: "memory");                \
    __builtin_amdgcn_s_barrier();                                              \
    asm volatile("s_waitcnt lgkmcnt(0)" ::: "memory");                         \
    __builtin_amdgcn_sched_barrier(0);                                         \
    __builtin_amdgcn_s_setprio(1);                                             \
    _Pragma("unroll")                                                          \
    for (int ks = 0; ks < 2; ++ks)                                             \
      _Pragma("unroll")                                                        \
      for (int i = 0; i < 4; ++i)                                              \
        _Pragma("unroll")                                                      \
        for (int n = 0; n < 2; ++n)                                            \
          acc[(qm)*4 + i][(qn)*2 + n] = __builtin_amdgcn_mfma_f32_16x16x32_bf16( \
              aF[i][ks], b_[n][ks], acc[(qm)*4 + i][(qn)*2 + n], 0, 0, 0);     \
    __builtin_amdgcn_s_setprio(0);                                             \
    __builtin_amdgcn_s_barrier();                                              \
  }

  STG_A(0, 0, 0);
  STG_B(0, 0, 0);
  STG_A(0, 1, 0);
  STG_B(0, 1, 0);
  STG_B(1, 0, 1);
  asm volatile("s_waitcnt vmcnt(2)" ::: "memory");
  __builtin_amdgcn_s_barrier();

#pragma unroll 1
  for (int j = 0; j < 8; ++j) {
    const int t1 = 2 * j + 1;
    const int t2 = 2 * j + 2;
    const int t3 = 2 * j + 3;
    DO_PHASE(0, 0, 0, 1, { STG_A(1, 0, t1); }, 0);
    DO_PHASE(0, 1, 0, 0, { STG_A(1, 1, t1); }, 0);
    DO_PHASE(1, 0, 0, 1, { STG_B(1, 1, t1); }, 0);
    DO_PHASE(1, 1, 0, 0, { if (t2 < 16) STG_B(0, 0, t2); }, 1);
    DO_PHASE(0, 0, 1, 1, { if (t2 < 16) STG_A(0, 0, t2); }, 0);
    DO_PHASE(0, 1, 1, 0, { if (t2 < 16) STG_A(0, 1, t2); }, 0);
    DO_PHASE(1, 0, 1, 1, { if (t2 < 16) STG_B(0, 1, t2); }, 0);
    DO_PHASE(1, 1, 1, 0, { if (t3 < 16) STG_B(1, 0, t3); }, 1);
  }

  const int orow0 = bm * 256 + wr * 128 + lg * 4;
  const int ocol0 = bn * 256 + wc * 64 + l15;
#pragma unroll
  for (int mi = 0; mi < 8; ++mi)
#pragma unroll
    for (int ni = 0; ni < 4; ++ni)
#pragma unroll
      for (int r = 0; r < 4; ++r)
        C[(size_t)(orow0 + mi * 16 + r) * NQKV + ocol0 + ni * 16] = f2bf(acc[mi][ni][r]);
#undef STG_A
#undef STG_B
#undef DO_PHASE
}

// ---------------------------------------------------------------------------
// Fallback fp32-input GEMM for small ws (round-1 verified).
// ---------------------------------------------------------------------------
__global__ __launch_bounds__(256) void qkv_gemm(const float* __restrict__ X,
                                                const float* __restrict__ W,
                                                unsigned short* __restrict__ QKV) {
  __shared__ unsigned short sA[128 * 32];
  __shared__ unsigned short sB[128 * 32];
  const int tid  = threadIdx.x;
  const int lane = tid & 63;
  const int wave = tid >> 6;
  const int wr = wave >> 1, wc = wave & 1;
  const int row0 = blockIdx.x * 128;
  const int col0 = blockIdx.y * 128;

  f32x4 acc[4][4];
#pragma unroll
  for (int i = 0; i < 4; ++i)
#pragma unroll
    for (int j = 0; j < 4; ++j)
#pragma unroll
      for (int r = 0; r < 4; ++r) acc[i][j][r] = 0.f;

  const int srow = tid >> 1;
  const int scol = (tid & 1) * 16;
  union U16 { unsigned short s[8]; uint4 v; };

#pragma unroll 1
  for (int k0 = 0; k0 < D_MODEL; k0 += 32) {
    {
      const float* ga = X + (size_t)(row0 + srow) * D_MODEL + k0 + scol;
      const float* gb = W + (size_t)(col0 + srow) * D_MODEL + k0 + scol;
      float va[16], vb[16];
#pragma unroll
      for (int i = 0; i < 4; ++i) {
        float4 t = ((const float4*)ga)[i];
        va[4*i+0] = t.x; va[4*i+1] = t.y; va[4*i+2] = t.z; va[4*i+3] = t.w;
        float4 u = ((const float4*)gb)[i];
        vb[4*i+0] = u.x; vb[4*i+1] = u.y; vb[4*i+2] = u.z; vb[4*i+3] = u.w;
      }
      U16 ua0, ua1, ub0, ub1;
#pragma unroll
      for (int e = 0; e < 8; ++e) {
        ua0.s[e] = f2bf(va[e]);   ua1.s[e] = f2bf(va[8 + e]);
        ub0.s[e] = f2bf(vb[e]);   ub1.s[e] = f2bf(vb[8 + e]);
      }
      *(uint4*)&sA[srow * 32 + scol + 0] = ua0.v;
      *(uint4*)&sA[srow * 32 + scol + 8] = ua1.v;
      *(uint4*)&sB[srow * 32 + scol + 0] = ub0.v;
      *(uint4*)&sB[srow * 32 + scol + 8] = ub1.v;
    }
    __syncthreads();

    const int lrow = lane & 15;
    const int lk   = (lane >> 4) * 8;
    bf16x8 av[4], bv[4];
#pragma unroll
    for (int i = 0; i < 4; ++i)
      av[i] = *(const bf16x8*)&sA[(wr * 64 + i * 16 + lrow) * 32 + lk];
#pragma unroll
    for (int j = 0; j < 4; ++j)
      bv[j] = *(const bf16x8*)&sB[(wc * 64 + j * 16 + lrow) * 32 + lk];
#pragma unroll
    for (int i = 0; i < 4; ++i)
#pragma unroll
      for (int j = 0; j < 4; ++j)
        acc[i][j] = __builtin_amdgcn_mfma_f32_16x16x32_bf16(av[i], bv[j], acc[i][j], 0, 0, 0);
    __syncthreads();
  }

  const int orow = row0 + wr * 64 + (lane >> 4) * 4;
  const int ocol = col0 + wc * 64 + (lane & 15);
#pragma unroll
  for (int i = 0; i < 4; ++i)
#pragma unroll
    for (int j = 0; j < 4; ++j)
#pragma unroll
      for (int r = 0; r < 4; ++r)
        QKV[(size_t)(orow + i * 16 + r) * NQKV + ocol + j * 16] = f2bf(acc[i][j][r]);
}

// ---------------------------------------------------------------------------
// Causal flash attention attn13: 8-wave intra-block key-split.
// Block = 512 thr = 8 waves: wq = wave&3 (32-q strip), ws = wave>>2 (key
// subtile role). Per 128-key pair, wave (wq,ws) processes only subtile ws
// (half of attn12's per-wave work) -> 16 waves/CU = 4/SIMD latency hiding.
// Per-wave state (m, ll, O) merged at the end via LDS (two-way softmax
// merge; ws=1 & wq<2 waves skip the diagonal tail: keys fully masked).
// Core machinery (swizzle, K-row permute, pfrag, MUPDATE) = attn12 verbatim.
// ---------------------------------------------------------------------------
__global__ __launch_bounds__(512, 4) void attn13(const unsigned short* __restrict__ QKV,
                                                 float* __restrict__ Out) {
  __shared__ unsigned short sK [2][2][64 * 64];   // 32 KB (merge scratch wq 0,1)
  __shared__ unsigned short sVt[2][2][64 * 64];   // 32 KB (merge scratch wq 2,3)

  const int tid  = threadIdx.x;
  const int lane = tid & 63;
  const int wave = tid >> 6;            // 0..7
  const int wq   = wave & 3;            // q-strip
  const int ws   = wave >> 2;           // key-subtile role
  const int l31  = lane & 31;
  const int hi   = lane >> 5;

  const int x = blockIdx.x;
  int bh, u;
  if (x < 256) { bh = x & 31; u = x >> 5; }
  else         { const int x2 = x - 256; bh = x2 & 31; u = 15 - (x2 >> 5); }

  const int b = bh >> 4, h = bh & 15;
  const int q0w  = u * 128 + wq * 32;
  const int qcol = q0w + l31;

  const unsigned short* Qbase = QKV + (size_t)(b * TOKENS) * NQKV + h * HDIM;
  const unsigned short* Kbase = Qbase + D_MODEL;
  const unsigned short* Vbase = Kbase + D_MODEL;

  bf16x8 qf[4];
  {
    const unsigned short* qrow = Qbase + (size_t)qcol * NQKV + hi * 8;
    union { unsigned short us[8]; bf16x8 v; ushort4 q[2]; } t;
#pragma unroll
    for (int dk = 0; dk < 4; ++dk) {
      t.q[0] = ((const ushort4*)(qrow + dk * 16))[0];
      t.q[1] = ((const ushort4*)(qrow + dk * 16))[1];
#pragma unroll
      for (int e = 0; e < 8; ++e) t.us[e] = f2bf(bf2f(t.us[e]) * SCALE);
      qf[dk] = t.v;
    }
  }

  f32x16 o0a, o0b, o1a, o1b;
#pragma unroll
  for (int r = 0; r < 16; ++r) { o0a[r] = 0.f; o0b[r] = 0.f; o1a[r] = 0.f; o1b[r] = 0.f; }
  float m = -1e30f, ll = 0.f;

  // ---- staging maps (512 threads) ----
  const int kd    = tid * 16;                       // K: byte offset in 8KB subtile
  const int krow  = kd >> 7;
  const int kgrow = (krow & 51) | ((krow & 4) << 1) | ((krow & 8) >> 1);
  const int kcb   = (kd & 127) ^ ((krow & 7) << 4);
  const int vk0   = (tid & 31) * 2;                 // V: 2 keys
  const int vd0   = (tid >> 5) * 4;                 // V: 4 dims
  union VU { ushort4 v; unsigned short us[4]; };
  VU va0, va1, vb0, vb1;

#define KGLOAD(kt, buf, s)                                                     \
  GLOAD16(Kbase + (size_t)((kt) * 64 + kgrow) * NQKV + (kcb >> 1),             \
          (char*)&sK[buf][s][0] + kd);

#define VLOADP(pp)                                                             \
  {                                                                            \
    const unsigned short* vsA = Vbase + (size_t)((2*(pp)) * 64 + vk0) * NQKV + vd0;   \
    va0.v = *(const ushort4*)(vsA);                                            \
    va1.v = *(const ushort4*)(vsA + NQKV);                                     \
    const unsigned short* vsB = Vbase + (size_t)((2*(pp)+1) * 64 + vk0) * NQKV + vd0; \
    vb0.v = *(const ushort4*)(vsB);                                            \
    vb1.v = *(const ushort4*)(vsB + NQKV);                                     \
  }

#define VWRITEP(buf)                                                           \
  {                                                                            \
    char* dA = (char*)&sVt[buf][0][0];                                         \
    char* dB = (char*)&sVt[buf][1][0];                                         \
    _Pragma("unroll")                                                          \
    for (int e = 0; e < 4; ++e) {                                              \
      const int dim = vd0 + e;                                                 \
      const int o2 = (dim * 128 + vk0 * 2) ^ ((dim & 7) << 4);                 \
      *(unsigned*)(dA + o2) = (unsigned)va0.us[e] | ((unsigned)va1.us[e] << 16); \
      *(unsigned*)(dB + o2) = (unsigned)vb0.us[e] | ((unsigned)vb1.us[e] << 16); \
    }                                                                          \
  }

#define QKT(cK, rowbase, st)                                                   \
  {                                                                            \
    _Pragma("unroll")                                                          \
    for (int dk = 0; dk < 4; ++dk) {                                           \
      const int row = (rowbase);                                               \
      bf16x8 kf = *(const bf16x8*)((cK) + ((row * 128 + hi * 16 + dk * 32) ^ ((row & 7) << 4))); \
      st = __builtin_amdgcn_mfma_f32_32x32x16_bf16(kf, qf[dk], st, 0, 0, 0);   \
    }                                                                          \
  }

#define PV4(cV, bpX, bpY, koff)                                                \
  {                                                                            \
    const int r0 = l31, r1 = l31 + 32;                                         \
    bf16x8 vf;                                                                 \
    vf = *(const bf16x8*)((cV) + ((r0 * 128 + hi * 16 + (koff)) ^ ((r0 & 7) << 4)));      \
    o0a = __builtin_amdgcn_mfma_f32_32x32x16_bf16(vf, bpX, o0a, 0, 0, 0);      \
    vf = *(const bf16x8*)((cV) + ((r1 * 128 + hi * 16 + (koff)) ^ ((r1 & 7) << 4)));      \
    o1a = __builtin_amdgcn_mfma_f32_32x32x16_bf16(vf, bpX, o1a, 0, 0, 0);      \
    vf = *(const bf16x8*)((cV) + ((r0 * 128 + hi * 16 + (koff) + 32) ^ ((r0 & 7) << 4))); \
    o0b = __builtin_amdgcn_mfma_f32_32x32x16_bf16(vf, bpY, o0b, 0, 0, 0);      \
    vf = *(const bf16x8*)((cV) + ((r1 * 128 + hi * 16 + (koff) + 32) ^ ((r1 & 7) << 4))); \
    o1b = __builtin_amdgcn_mfma_f32_32x32x16_bf16(vf, bpY, o1b, 0, 0, 0);      \
  }

#define MUPDATE(mx)                                                            \
  {                                                                            \
    if (!__all((mx) - m <= 8.f)) {                                             \
      float mw = fmaxf((mx), xchg32(mx));                                      \
      const float mnew = fmaxf(m, mw);                                         \
      const float corr = exp2f(m - mnew);                                      \
      m = mnew;                                                                \
      ll *= corr;                                                              \
      _Pragma("unroll")                                                        \
      for (int r = 0; r < 16; ++r) {                                           \
        o0a[r] *= corr; o0b[r] *= corr; o1a[r] *= corr; o1b[r] *= corr;        \
      }                                                                        \
    }                                                                          \
  }

  // ---- prologue: stage pair 0 ----
  KGLOAD(0, 0, 0);
  KGLOAD(1, 0, 1);
  VLOADP(0);
  VWRITEP(0);
  __syncthreads();

  // ---- steady pairs (no diagonal; wave computes only its subtile ws) ----
#pragma unroll 1
  for (int p = 0; p < u; ++p) {
    const int cur = p & 1;
    KGLOAD(2 * (p + 1),     cur ^ 1, 0);
    KGLOAD(2 * (p + 1) + 1, cur ^ 1, 1);
    VLOADP(p + 1);

    {
      const char* cK = (const char*)&sK[cur][ws][0];
      const char* cV = (const char*)&sVt[cur][ws][0];
      f32x16 st0, st1;
#pragma unroll
      for (int r = 0; r < 16; ++r) { st0[r] = 0.f; st1[r] = 0.f; }
      QKT(cK, l31,      st0);
      QKT(cK, l31 + 32, st1);
      float mx = max32t(st0, st1);
      MUPDATE(mx);
      float p0[16], p1[16];
#pragma unroll
      for (int r = 0; r < 16; ++r) { p0[r] = exp2f(st0[r] - m); p1[r] = exp2f(st1[r] - m); }
      ll += sum32t(p0, p1);
      bf16x8 f0 = pfrag8(&p0[0]), f1 = pfrag8(&p0[8]);
      bf16x8 f2 = pfrag8(&p1[0]), f3 = pfrag8(&p1[8]);
      PV4(cV, f0, f1, 0);
      PV4(cV, f2, f3, 64);
    }

    VWRITEP(cur ^ 1);
    __syncthreads();
  }

  // ---- diagonal pair p = u (per-(ws,wq) flags; ws=1 & wq<2 fully masked) ----
  {
    const int cur = u & 1;
    const bool skip = (ws == 1) && (wq < 2);
    if (!skip) {
      const bool diag  = (ws == 0) ? (wq < 2) : true;
      const bool do_hi = diag ? ((wq & 1) == 1) : true;
      const int kbase = u * 128 + ws * 64;
      const char* cK = (const char*)&sK[cur][ws][0];
      const char* cV = (const char*)&sVt[cur][ws][0];

      f32x16 st0, st1;
#pragma unroll
      for (int r = 0; r < 16; ++r) { st0[r] = 0.f; st1[r] = 0.f; }
      QKT(cK, l31, st0);
      if (do_hi) QKT(cK, l31 + 32, st1);

      if (diag) {
#pragma unroll
        for (int r = 0; r < 16; ++r) {
          const int key0 = kbase + (r & 7) + ((r & 8) << 1) + 8 * hi;
          if (key0 > qcol) st0[r] = -1e30f;
          if (do_hi && key0 + 32 > qcol) st1[r] = -1e30f;
        }
      }

      float mx = do_hi ? max32t(st0, st1) : max32t(st0, st0);
      MUPDATE(mx);

      float p0[16], p1[16];
#pragma unroll
      for (int r = 0; r < 16; ++r) p0[r] = exp2f(st0[r] - m);
      if (do_hi) {
#pragma unroll
        for (int r = 0; r < 16; ++r) p1[r] = exp2f(st1[r] - m);
        ll += sum32t(p0, p1);
      } else {
        float z[16];
#pragma unroll
        for (int r = 0; r < 16; ++r) z[r] = 0.f;
        ll += sum32t(p0, z);
      }

      bf16x8 c0 = pfrag8(&p0[0]), c1 = pfrag8(&p0[8]);
      PV4(cV, c0, c1, 0);
      if (do_hi) {
        bf16x8 c2 = pfrag8(&p1[0]), c3 = pfrag8(&p1[8]);
        PV4(cV, c2, c3, 64);
      }
    }
  }

  // ---- merge A/B wave pairs via LDS, then write output ----
  __syncthreads();                       // all compute done reading K/V LDS
  const float lfull = ll + xchg32(ll);   // merge this wave's two key-halves
#pragma unroll
  for (int r = 0; r < 16; ++r) { o0a[r] += o0b[r]; o1a[r] += o1b[r]; }

  float* slot = (wq < 2)
      ? ((float*)&sK [0][0][0] + (size_t)(( wq      * 64 + lane) * 35))
      : ((float*)&sVt[0][0][0] + (size_t)(((wq - 2) * 64 + lane) * 35));

  if (ws == 1) {
    slot[0] = m;
    slot[1] = lfull;
#pragma unroll
    for (int r = 0; r < 16; ++r) slot[2 + r]  = o0a[r];
#pragma unroll
    for (int r = 0; r < 16; ++r) slot[18 + r] = o1a[r];
  }
  __syncthreads();
  if (ws == 0) {
    const float mB = slot[0];
    const float lB = slot[1];
    const float M  = fmaxf(m, mB);
    const float wA = exp2f(m - M);
    const float wB = exp2f(mB - M);
    const float inv = 1.f / (lfull * wA + lB * wB);
    float* orow = Out + (size_t)(b * TOKENS + qcol) * D_MODEL + h * HDIM;
#pragma unroll
    for (int g = 0; g < 4; ++g) {
      float4 w0, w1;
      w0.x = (o0a[4*g+0] * wA + slot[2 + 4*g+0] * wB) * inv;
      w0.y = (o0a[4*g+1] * wA + slot[2 + 4*g+1] * wB) * inv;
      w0.z = (o0a[4*g+2] * wA + slot[2 + 4*g+2] * wB) * inv;
      w0.w = (o0a[4*g+3] * wA + slot[2 + 4*g+3] * wB) * inv;
      w1.x = (o1a[4*g+0] * wA + slot[18 + 4*g+0] * wB) * inv;
      w1.y = (o1a[4*g+1] * wA + slot[18 + 4*g+1] * wB) * inv;
      w1.z = (o1a[4*g+2] * wA + slot[18 + 4*g+2] * wB) * inv;
      w1.w = (o1a[4*g+3] * wA + slot[18 + 4*g+3] * wB) * inv;
      *(float4*)(orow + 8 * g + 4 * hi)      = w0;
      *(float4*)(orow + 8 * g + 4 * hi + 32) = w1;
    }
  }
#undef KGLOAD
#undef VLOADP
#undef VWRITEP
#undef QKT
#undef PV4
#undef MUPDATE
}

extern "C" void kernel_launch(void* const* d_in, const int* in_sizes, int n_in,
                              void* d_out, int out_size, void* d_ws, size_t ws_size,
                              hipStream_t stream) {
  const float* X = (const float*)d_in[0];
  const float* W = (const float*)d_in[1];
  float* Out = (float*)d_out;
  unsigned short* QKV = (unsigned short*)d_ws;

  const size_t QKV_E = (size_t)MROWS * NQKV;
  const size_t XB_E  = (size_t)MROWS * D_MODEL;
  const size_t WB_E  = (size_t)NQKV * D_MODEL;
  const size_t need_bf16 = (QKV_E + XB_E + WB_E) * 2;

  if (ws_size >= need_bf16) {
    unsigned short* Xb = QKV + QKV_E;
    unsigned short* Wb = Xb + XB_E;
    cvt_bf16<<<(XB_E + WB_E) / (256 * 8), 256, 0, stream>>>(X, W, Xb, Wb);
    gemm8<<<dim3(MROWS / 256, NQKV / 256), 512, 0, stream>>>(Xb, Wb, QKV);
  } else {
    qkv_gemm<<<dim3(MROWS / 128, NQKV / 128), 256, 0, stream>>>(X, W, QKV);
  }

  attn13<<<512, 512, 0, stream>>>(QKV, Out);
}

// Round 22
// 94.187 us; speedup vs baseline: 2.2693x; 2.2693x over previous
//
#include <hip/hip_runtime.h>
#include <hip/hip_bf16.h>
#include <stdint.h>

#define D_MODEL 1024
#define TOKENS  2048
#define HEADS   16
#define HDIM    64
#define NQKV    3072      // 3*D_MODEL
#define MROWS   4096      // BATCH*TOKENS
#define SCALE   0.18033688011112042f   // 0.125 * log2(e)

typedef __attribute__((ext_vector_type(4)))  float f32x4;
typedef __attribute__((ext_vector_type(16))) float f32x16;
typedef __attribute__((ext_vector_type(8)))  short bf16x8;

__device__ __forceinline__ unsigned short f2bf(float f) {
  union { float f; unsigned u; } v; v.f = f;
  unsigned u = v.u + 0x7FFFu + ((v.u >> 16) & 1u);   // RNE
  return (unsigned short)(u >> 16);
}
__device__ __forceinline__ float bf2f(unsigned short b) {
  union { unsigned u; float f; } v; v.u = ((unsigned)b) << 16;
  return v.f;
}
__device__ __forceinline__ unsigned cvt_pk_bf16(float lo, float hi) {
  unsigned r;
  asm("v_cvt_pk_bf16_f32 %0, %1, %2" : "=v"(r) : "v"(lo), "v"(hi));
  return r;
}
__device__ __forceinline__ float xchg32(float v) {
  return __shfl_xor(v, 32);
}
__device__ __forceinline__ bf16x8 pfrag8(const float* g) {
  union { uint4 u; bf16x8 v; } r;
  r.u.x = cvt_pk_bf16(g[0], g[1]);
  r.u.y = cvt_pk_bf16(g[2], g[3]);
  r.u.z = cvt_pk_bf16(g[4], g[5]);
  r.u.w = cvt_pk_bf16(g[6], g[7]);
  return r.v;
}
__device__ __forceinline__ float max32t(const f32x16& a, const f32x16& b) {
  float t[16];
#pragma unroll
  for (int r = 0; r < 16; ++r) t[r] = fmaxf(a[r], b[r]);
#pragma unroll
  for (int s = 8; s > 0; s >>= 1)
#pragma unroll
    for (int r = 0; r < s; ++r) t[r] = fmaxf(t[r], t[r + s]);
  return t[0];
}
__device__ __forceinline__ float sum32t(const float* a, const float* b) {
  float t[16];
#pragma unroll
  for (int r = 0; r < 16; ++r) t[r] = a[r] + b[r];
#pragma unroll
  for (int s = 8; s > 0; s >>= 1)
#pragma unroll
    for (int r = 0; r < s; ++r) t[r] = t[r] + t[r + s];
  return t[0];
}

#define GLOAD16(g, l)                                                          \
  __builtin_amdgcn_global_load_lds(                                            \
      (const __attribute__((address_space(1))) unsigned int*)(g),              \
      (__attribute__((address_space(3))) unsigned int*)(l), 16, 0, 0)

// ---------------------------------------------------------------------------
// fp32 -> bf16 convert pass (X then W, contiguous).
// ---------------------------------------------------------------------------
__global__ __launch_bounds__(256) void cvt_bf16(const float* __restrict__ X,
                                                const float* __restrict__ W,
                                                unsigned short* __restrict__ Xb,
                                                unsigned short* __restrict__ Wb) {
  const size_t NX = (size_t)MROWS * D_MODEL;
  size_t i = ((size_t)blockIdx.x * 256 + threadIdx.x) * 8;
  const float* src; unsigned short* dst; size_t off;
  if (i < NX) { src = X; dst = Xb; off = i; }
  else        { src = W; dst = Wb; off = i - NX; }
  float4 a = ((const float4*)(src + off))[0];
  float4 b = ((const float4*)(src + off))[1];
  union { unsigned short s[8]; uint4 v; } u;
  u.s[0] = f2bf(a.x); u.s[1] = f2bf(a.y); u.s[2] = f2bf(a.z); u.s[3] = f2bf(a.w);
  u.s[4] = f2bf(b.x); u.s[5] = f2bf(b.y); u.s[6] = f2bf(b.z); u.s[7] = f2bf(b.w);
  *(uint4*)(dst + off) = u.v;
}

// ---------------------------------------------------------------------------
// 8-phase 256x256 GEMM (round-17 verified: full swizzle + A-frag reuse).
// ---------------------------------------------------------------------------
__global__ __launch_bounds__(512, 1) void gemm8(const unsigned short* __restrict__ A,
                                                const unsigned short* __restrict__ B,
                                                unsigned short* __restrict__ C) {
  __shared__ unsigned short sA[2][2][128][64];
  __shared__ unsigned short sB[2][2][128][64];

  const int tid  = threadIdx.x;
  const int lane = tid & 63;
  const int wave = tid >> 6;
  const int wr   = wave >> 2;
  const int wc   = wave & 3;
  const int l15  = lane & 15;
  const int lg   = lane >> 4;

  const int bm = blockIdx.x;
  const int bn = blockIdx.y;

  f32x4 acc[8][4];
#pragma unroll
  for (int i = 0; i < 8; ++i)
#pragma unroll
    for (int j = 0; j < 4; ++j)
#pragma unroll
      for (int r = 0; r < 4; ++r) acc[i][j][r] = 0.f;

  const int srow = tid >> 3;
  const int scb  = (tid & 7) * 16;
  const int ssce = (scb ^ ((srow & 7) << 4)) >> 1;

  const unsigned short* Ag = A + (size_t)(bm * 256) * D_MODEL;
  const unsigned short* Bg = B + (size_t)(bn * 256) * D_MODEL;

#define STG_A(buf, hf, t)                                                      \
  { GLOAD16(Ag + (size_t)((hf) * 128 + srow) * D_MODEL + (t) * 64 + ssce,      \
            (char*)&sA[buf][hf][0][0] + srow * 128 + scb);                     \
    GLOAD16(Ag + (size_t)((hf) * 128 + 64 + srow) * D_MODEL + (t) * 64 + ssce, \
            (char*)&sA[buf][hf][0][0] + 8192 + srow * 128 + scb); }
#define STG_B(buf, hf, t)                                                      \
  { GLOAD16(Bg + (size_t)((hf) * 128 + srow) * D_MODEL + (t) * 64 + ssce,      \
            (char*)&sB[buf][hf][0][0] + srow * 128 + scb);                     \
    GLOAD16(Bg + (size_t)((hf) * 128 + 64 + srow) * D_MODEL + (t) * 64 + ssce, \
            (char*)&sB[buf][hf][0][0] + 8192 + srow * 128 + scb); }

  const char* aBse[2] = { (const char*)&sA[0][wr][0][0], (const char*)&sA[1][wr][0][0] };
  const char* bBse[2] = { (const char*)&sB[0][wc >> 1][0][0], (const char*)&sB[1][wc >> 1][0][0] };
  const int swzl = (l15 & 7) << 4;
  const int cbs0 = (lg * 16) ^ swzl;
  const int cbs1 = (64 + lg * 16) ^ swzl;
  const int arow = l15 * 128;
  const int brow = ((wc & 1) * 64 + l15) * 128;

  bf16x8 aF[4][2];

#define DO_PHASE(qm, qn, buf, LD_A, STAGE_STMT, DO_VM)                         \
  {                                                                            \
    if (LD_A) {                                                                \
      _Pragma("unroll")                                                        \
      for (int i = 0; i < 4; ++i) {                                            \
        aF[i][0] = *(const bf16x8*)(aBse[buf] + ((qm)*4 + i) * 2048 + arow + cbs0); \
        aF[i][1] = *(const bf16x8*)(aBse[buf] + ((qm)*4 + i) * 2048 + arow + cbs1); \
      }                                                                        \
    }                                                                          \
    bf16x8 b_[2][2];                                                           \
    _Pragma("unroll")                                                          \
    for (int n = 0; n < 2; ++n) {                                              \
      b_[n][0] = *(const bf16x8*)(bBse[buf] + ((qn)*2 + n) * 2048 + brow + cbs0); \
      b_[n][1] = *(const bf16x8*)(bBse[buf] + ((qn)*2 + n) * 2048 + brow + cbs1); \
    }                                                                          \
    STAGE_STMT;                                                                \
    if (DO_VM) asm volatile("s_waitcnt vmcnt(2)" ::: "memory");                \
    __builtin_amdgcn_s_barrier();                                              \
    asm volatile("s_waitcnt lgkmcnt(0)" ::: "memory");                         \
    __builtin_amdgcn_sched_barrier(0);                                         \
    __builtin_amdgcn_s_setprio(1);                                             \
    _Pragma("unroll")                                                          \
    for (int ks = 0; ks < 2; ++ks)                                             \
      _Pragma("unroll")                                                        \
      for (int i = 0; i < 4; ++i)                                              \
        _Pragma("unroll")                                                      \
        for (int n = 0; n < 2; ++n)                                            \
          acc[(qm)*4 + i][(qn)*2 + n] = __builtin_amdgcn_mfma_f32_16x16x32_bf16( \
              aF[i][ks], b_[n][ks], acc[(qm)*4 + i][(qn)*2 + n], 0, 0, 0);     \
    __builtin_amdgcn_s_setprio(0);                                             \
    __builtin_amdgcn_s_barrier();                                              \
  }

  STG_A(0, 0, 0);
  STG_B(0, 0, 0);
  STG_A(0, 1, 0);
  STG_B(0, 1, 0);
  STG_B(1, 0, 1);
  asm volatile("s_waitcnt vmcnt(2)" ::: "memory");
  __builtin_amdgcn_s_barrier();

#pragma unroll 1
  for (int j = 0; j < 8; ++j) {
    const int t1 = 2 * j + 1;
    const int t2 = 2 * j + 2;
    const int t3 = 2 * j + 3;
    DO_PHASE(0, 0, 0, 1, { STG_A(1, 0, t1); }, 0);
    DO_PHASE(0, 1, 0, 0, { STG_A(1, 1, t1); }, 0);
    DO_PHASE(1, 0, 0, 1, { STG_B(1, 1, t1); }, 0);
    DO_PHASE(1, 1, 0, 0, { if (t2 < 16) STG_B(0, 0, t2); }, 1);
    DO_PHASE(0, 0, 1, 1, { if (t2 < 16) STG_A(0, 0, t2); }, 0);
    DO_PHASE(0, 1, 1, 0, { if (t2 < 16) STG_A(0, 1, t2); }, 0);
    DO_PHASE(1, 0, 1, 1, { if (t2 < 16) STG_B(0, 1, t2); }, 0);
    DO_PHASE(1, 1, 1, 0, { if (t3 < 16) STG_B(1, 0, t3); }, 1);
  }

  const int orow0 = bm * 256 + wr * 128 + lg * 4;
  const int ocol0 = bn * 256 + wc * 64 + l15;
#pragma unroll
  for (int mi = 0; mi < 8; ++mi)
#pragma unroll
    for (int ni = 0; ni < 4; ++ni)
#pragma unroll
      for (int r = 0; r < 4; ++r)
        C[(size_t)(orow0 + mi * 16 + r) * NQKV + ocol0 + ni * 16] = f2bf(acc[mi][ni][r]);
#undef STG_A
#undef STG_B
#undef DO_PHASE
}

// ---------------------------------------------------------------------------
// Fallback fp32-input GEMM for small ws (round-1 verified).
// ---------------------------------------------------------------------------
__global__ __launch_bounds__(256) void qkv_gemm(const float* __restrict__ X,
                                                const float* __restrict__ W,
                                                unsigned short* __restrict__ QKV) {
  __shared__ unsigned short sA[128 * 32];
  __shared__ unsigned short sB[128 * 32];
  const int tid  = threadIdx.x;
  const int lane = tid & 63;
  const int wave = tid >> 6;
  const int wr = wave >> 1, wc = wave & 1;
  const int row0 = blockIdx.x * 128;
  const int col0 = blockIdx.y * 128;

  f32x4 acc[4][4];
#pragma unroll
  for (int i = 0; i < 4; ++i)
#pragma unroll
    for (int j = 0; j < 4; ++j)
#pragma unroll
      for (int r = 0; r < 4; ++r) acc[i][j][r] = 0.f;

  const int srow = tid >> 1;
  const int scol = (tid & 1) * 16;
  union U16 { unsigned short s[8]; uint4 v; };

#pragma unroll 1
  for (int k0 = 0; k0 < D_MODEL; k0 += 32) {
    {
      const float* ga = X + (size_t)(row0 + srow) * D_MODEL + k0 + scol;
      const float* gb = W + (size_t)(col0 + srow) * D_MODEL + k0 + scol;
      float va[16], vb[16];
#pragma unroll
      for (int i = 0; i < 4; ++i) {
        float4 t = ((const float4*)ga)[i];
        va[4*i+0] = t.x; va[4*i+1] = t.y; va[4*i+2] = t.z; va[4*i+3] = t.w;
        float4 u = ((const float4*)gb)[i];
        vb[4*i+0] = u.x; vb[4*i+1] = u.y; vb[4*i+2] = u.z; vb[4*i+3] = u.w;
      }
      U16 ua0, ua1, ub0, ub1;
#pragma unroll
      for (int e = 0; e < 8; ++e) {
        ua0.s[e] = f2bf(va[e]);   ua1.s[e] = f2bf(va[8 + e]);
        ub0.s[e] = f2bf(vb[e]);   ub1.s[e] = f2bf(vb[8 + e]);
      }
      *(uint4*)&sA[srow * 32 + scol + 0] = ua0.v;
      *(uint4*)&sA[srow * 32 + scol + 8] = ua1.v;
      *(uint4*)&sB[srow * 32 + scol + 0] = ub0.v;
      *(uint4*)&sB[srow * 32 + scol + 8] = ub1.v;
    }
    __syncthreads();

    const int lrow = lane & 15;
    const int lk   = (lane >> 4) * 8;
    bf16x8 av[4], bv[4];
#pragma unroll
    for (int i = 0; i < 4; ++i)
      av[i] = *(const bf16x8*)&sA[(wr * 64 + i * 16 + lrow) * 32 + lk];
#pragma unroll
    for (int j = 0; j < 4; ++j)
      bv[j] = *(const bf16x8*)&sB[(wc * 64 + j * 16 + lrow) * 32 + lk];
#pragma unroll
    for (int i = 0; i < 4; ++i)
#pragma unroll
      for (int j = 0; j < 4; ++j)
        acc[i][j] = __builtin_amdgcn_mfma_f32_16x16x32_bf16(av[i], bv[j], acc[i][j], 0, 0, 0);
    __syncthreads();
  }

  const int orow = row0 + wr * 64 + (lane >> 4) * 4;
  const int ocol = col0 + wc * 64 + (lane & 15);
#pragma unroll
  for (int i = 0; i < 4; ++i)
#pragma unroll
    for (int j = 0; j < 4; ++j)
#pragma unroll
      for (int r = 0; r < 4; ++r)
        QKV[(size_t)(orow + i * 16 + r) * NQKV + ocol + j * 16] = f2bf(acc[i][j][r]);
}

// ---------------------------------------------------------------------------
// Causal flash attention attn13 (round-21 logic, correctness-verified), with
// the register budget fixed: __launch_bounds__(512, 2) -> natural ~110 VGPR,
// no spill; 2 blocks/CU still possible since VGPR <= 128.
// ---------------------------------------------------------------------------
__global__ __launch_bounds__(512, 2) void attn13(const unsigned short* __restrict__ QKV,
                                                 float* __restrict__ Out) {
  __shared__ unsigned short sK [2][2][64 * 64];   // 32 KB (merge scratch wq 0,1)
  __shared__ unsigned short sVt[2][2][64 * 64];   // 32 KB (merge scratch wq 2,3)

  const int tid  = threadIdx.x;
  const int lane = tid & 63;
  const int wave = tid >> 6;            // 0..7
  const int wq   = wave & 3;            // q-strip
  const int ws   = wave >> 2;           // key-subtile role
  const int l31  = lane & 31;
  const int hi   = lane >> 5;

  const int x = blockIdx.x;
  int bh, u;
  if (x < 256) { bh = x & 31; u = x >> 5; }
  else         { const int x2 = x - 256; bh = x2 & 31; u = 15 - (x2 >> 5); }

  const int b = bh >> 4, h = bh & 15;
  const int q0w  = u * 128 + wq * 32;
  const int qcol = q0w + l31;

  const unsigned short* Qbase = QKV + (size_t)(b * TOKENS) * NQKV + h * HDIM;
  const unsigned short* Kbase = Qbase + D_MODEL;
  const unsigned short* Vbase = Kbase + D_MODEL;

  bf16x8 qf[4];
  {
    const unsigned short* qrow = Qbase + (size_t)qcol * NQKV + hi * 8;
    union { unsigned short us[8]; bf16x8 v; ushort4 q[2]; } t;
#pragma unroll
    for (int dk = 0; dk < 4; ++dk) {
      t.q[0] = ((const ushort4*)(qrow + dk * 16))[0];
      t.q[1] = ((const ushort4*)(qrow + dk * 16))[1];
#pragma unroll
      for (int e = 0; e < 8; ++e) t.us[e] = f2bf(bf2f(t.us[e]) * SCALE);
      qf[dk] = t.v;
    }
  }

  f32x16 o0a, o0b, o1a, o1b;
#pragma unroll
  for (int r = 0; r < 16; ++r) { o0a[r] = 0.f; o0b[r] = 0.f; o1a[r] = 0.f; o1b[r] = 0.f; }
  float m = -1e30f, ll = 0.f;

  // ---- staging maps (512 threads) ----
  const int kd    = tid * 16;                       // K: byte offset in 8KB subtile
  const int krow  = kd >> 7;
  const int kgrow = (krow & 51) | ((krow & 4) << 1) | ((krow & 8) >> 1);
  const int kcb   = (kd & 127) ^ ((krow & 7) << 4);
  const int vk0   = (tid & 31) * 2;                 // V: 2 keys
  const int vd0   = (tid >> 5) * 4;                 // V: 4 dims
  union VU { ushort4 v; unsigned short us[4]; };
  VU va0, va1, vb0, vb1;

#define KGLOAD(kt, buf, s)                                                     \
  GLOAD16(Kbase + (size_t)((kt) * 64 + kgrow) * NQKV + (kcb >> 1),             \
          (char*)&sK[buf][s][0] + kd);

#define VLOADP(pp)                                                             \
  {                                                                            \
    const unsigned short* vsA = Vbase + (size_t)((2*(pp)) * 64 + vk0) * NQKV + vd0;   \
    va0.v = *(const ushort4*)(vsA);                                            \
    va1.v = *(const ushort4*)(vsA + NQKV);                                     \
    const unsigned short* vsB = Vbase + (size_t)((2*(pp)+1) * 64 + vk0) * NQKV + vd0; \
    vb0.v = *(const ushort4*)(vsB);                                            \
    vb1.v = *(const ushort4*)(vsB + NQKV);                                     \
  }

#define VWRITEP(buf)                                                           \
  {                                                                            \
    char* dA = (char*)&sVt[buf][0][0];                                         \
    char* dB = (char*)&sVt[buf][1][0];                                         \
    _Pragma("unroll")                                                          \
    for (int e = 0; e < 4; ++e) {                                              \
      const int dim = vd0 + e;                                                 \
      const int o2 = (dim * 128 + vk0 * 2) ^ ((dim & 7) << 4);                 \
      *(unsigned*)(dA + o2) = (unsigned)va0.us[e] | ((unsigned)va1.us[e] << 16); \
      *(unsigned*)(dB + o2) = (unsigned)vb0.us[e] | ((unsigned)vb1.us[e] << 16); \
    }                                                                          \
  }

#define QKT(cK, rowbase, st)                                                   \
  {                                                                            \
    _Pragma("unroll")                                                          \
    for (int dk = 0; dk < 4; ++dk) {                                           \
      const int row = (rowbase);                                               \
      bf16x8 kf = *(const bf16x8*)((cK) + ((row * 128 + hi * 16 + dk * 32) ^ ((row & 7) << 4))); \
      st = __builtin_amdgcn_mfma_f32_32x32x16_bf16(kf, qf[dk], st, 0, 0, 0);   \
    }                                                                          \
  }

#define PV4(cV, bpX, bpY, koff)                                                \
  {                                                                            \
    const int r0 = l31, r1 = l31 + 32;                                         \
    bf16x8 vf;                                                                 \
    vf = *(const bf16x8*)((cV) + ((r0 * 128 + hi * 16 + (koff)) ^ ((r0 & 7) << 4)));      \
    o0a = __builtin_amdgcn_mfma_f32_32x32x16_bf16(vf, bpX, o0a, 0, 0, 0);      \
    vf = *(const bf16x8*)((cV) + ((r1 * 128 + hi * 16 + (koff)) ^ ((r1 & 7) << 4)));      \
    o1a = __builtin_amdgcn_mfma_f32_32x32x16_bf16(vf, bpX, o1a, 0, 0, 0);      \
    vf = *(const bf16x8*)((cV) + ((r0 * 128 + hi * 16 + (koff) + 32) ^ ((r0 & 7) << 4))); \
    o0b = __builtin_amdgcn_mfma_f32_32x32x16_bf16(vf, bpY, o0b, 0, 0, 0);      \
    vf = *(const bf16x8*)((cV) + ((r1 * 128 + hi * 16 + (koff) + 32) ^ ((r1 & 7) << 4))); \
    o1b = __builtin_amdgcn_mfma_f32_32x32x16_bf16(vf, bpY, o1b, 0, 0, 0);      \
  }

#define MUPDATE(mx)                                                            \
  {                                                                            \
    if (!__all((mx) - m <= 8.f)) {                                             \
      float mw = fmaxf((mx), xchg32(mx));                                      \
      const float mnew = fmaxf(m, mw);                                         \
      const float corr = exp2f(m - mnew);                                      \
      m = mnew;                                                                \
      ll *= corr;                                                              \
      _Pragma("unroll")                                                        \
      for (int r = 0; r < 16; ++r) {                                           \
        o0a[r] *= corr; o0b[r] *= corr; o1a[r] *= corr; o1b[r] *= corr;        \
      }                                                                        \
    }                                                                          \
  }

  // ---- prologue: stage pair 0 ----
  KGLOAD(0, 0, 0);
  KGLOAD(1, 0, 1);
  VLOADP(0);
  VWRITEP(0);
  __syncthreads();

  // ---- steady pairs (no diagonal; wave computes only its subtile ws) ----
#pragma unroll 1
  for (int p = 0; p < u; ++p) {
    const int cur = p & 1;
    KGLOAD(2 * (p + 1),     cur ^ 1, 0);
    KGLOAD(2 * (p + 1) + 1, cur ^ 1, 1);
    VLOADP(p + 1);

    {
      const char* cK = (const char*)&sK[cur][ws][0];
      const char* cV = (const char*)&sVt[cur][ws][0];
      f32x16 st0, st1;
#pragma unroll
      for (int r = 0; r < 16; ++r) { st0[r] = 0.f; st1[r] = 0.f; }
      QKT(cK, l31,      st0);
      QKT(cK, l31 + 32, st1);
      float mx = max32t(st0, st1);
      MUPDATE(mx);
      float p0[16], p1[16];
#pragma unroll
      for (int r = 0; r < 16; ++r) { p0[r] = exp2f(st0[r] - m); p1[r] = exp2f(st1[r] - m); }
      ll += sum32t(p0, p1);
      bf16x8 f0 = pfrag8(&p0[0]), f1 = pfrag8(&p0[8]);
      bf16x8 f2 = pfrag8(&p1[0]), f3 = pfrag8(&p1[8]);
      PV4(cV, f0, f1, 0);
      PV4(cV, f2, f3, 64);
    }

    VWRITEP(cur ^ 1);
    __syncthreads();
  }

  // ---- diagonal pair p = u (per-(ws,wq) flags; ws=1 & wq<2 fully masked) ----
  {
    const int cur = u & 1;
    const bool skip = (ws == 1) && (wq < 2);
    if (!skip) {
      const bool diag  = (ws == 0) ? (wq < 2) : true;
      const bool do_hi = diag ? ((wq & 1) == 1) : true;
      const int kbase = u * 128 + ws * 64;
      const char* cK = (const char*)&sK[cur][ws][0];
      const char* cV = (const char*)&sVt[cur][ws][0];

      f32x16 st0, st1;
#pragma unroll
      for (int r = 0; r < 16; ++r) { st0[r] = 0.f; st1[r] = 0.f; }
      QKT(cK, l31, st0);
      if (do_hi) QKT(cK, l31 + 32, st1);

      if (diag) {
#pragma unroll
        for (int r = 0; r < 16; ++r) {
          const int key0 = kbase + (r & 7) + ((r & 8) << 1) + 8 * hi;
          if (key0 > qcol) st0[r] = -1e30f;
          if (do_hi && key0 + 32 > qcol) st1[r] = -1e30f;
        }
      }

      float mx = do_hi ? max32t(st0, st1) : max32t(st0, st0);
      MUPDATE(mx);

      float p0[16], p1[16];
#pragma unroll
      for (int r = 0; r < 16; ++r) p0[r] = exp2f(st0[r] - m);
      if (do_hi) {
#pragma unroll
        for (int r = 0; r < 16; ++r) p1[r] = exp2f(st1[r] - m);
        ll += sum32t(p0, p1);
      } else {
        float z[16];
#pragma unroll
        for (int r = 0; r < 16; ++r) z[r] = 0.f;
        ll += sum32t(p0, z);
      }

      bf16x8 c0 = pfrag8(&p0[0]), c1 = pfrag8(&p0[8]);
      PV4(cV, c0, c1, 0);
      if (do_hi) {
        bf16x8 c2 = pfrag8(&p1[0]), c3 = pfrag8(&p1[8]);
        PV4(cV, c2, c3, 64);
      }
    }
  }

  // ---- merge A/B wave pairs via LDS, then write output ----
  __syncthreads();                       // all compute done reading K/V LDS
  const float lfull = ll + xchg32(ll);   // merge this wave's two key-halves
#pragma unroll
  for (int r = 0; r < 16; ++r) { o0a[r] += o0b[r]; o1a[r] += o1b[r]; }

  float* slot = (wq < 2)
      ? ((float*)&sK [0][0][0] + (size_t)(( wq      * 64 + lane) * 35))
      : ((float*)&sVt[0][0][0] + (size_t)(((wq - 2) * 64 + lane) * 35));

  if (ws == 1) {
    slot[0] = m;
    slot[1] = lfull;
#pragma unroll
    for (int r = 0; r < 16; ++r) slot[2 + r]  = o0a[r];
#pragma unroll
    for (int r = 0; r < 16; ++r) slot[18 + r] = o1a[r];
  }
  __syncthreads();
  if (ws == 0) {
    const float mB = slot[0];
    const float lB = slot[1];
    const float M  = fmaxf(m, mB);
    const float wA = exp2f(m - M);
    const float wB = exp2f(mB - M);
    const float inv = 1.f / (lfull * wA + lB * wB);
    float* orow = Out + (size_t)(b * TOKENS + qcol) * D_MODEL + h * HDIM;
#pragma unroll
    for (int g = 0; g < 4; ++g) {
      float4 w0, w1;
      w0.x = (o0a[4*g+0] * wA + slot[2 + 4*g+0] * wB) * inv;
      w0.y = (o0a[4*g+1] * wA + slot[2 + 4*g+1] * wB) * inv;
      w0.z = (o0a[4*g+2] * wA + slot[2 + 4*g+2] * wB) * inv;
      w0.w = (o0a[4*g+3] * wA + slot[2 + 4*g+3] * wB) * inv;
      w1.x = (o1a[4*g+0] * wA + slot[18 + 4*g+0] * wB) * inv;
      w1.y = (o1a[4*g+1] * wA + slot[18 + 4*g+1] * wB) * inv;
      w1.z = (o1a[4*g+2] * wA + slot[18 + 4*g+2] * wB) * inv;
      w1.w = (o1a[4*g+3] * wA + slot[18 + 4*g+3] * wB) * inv;
      *(float4*)(orow + 8 * g + 4 * hi)      = w0;
      *(float4*)(orow + 8 * g + 4 * hi + 32) = w1;
    }
  }
#undef KGLOAD
#undef VLOADP
#undef VWRITEP
#undef QKT
#undef PV4
#undef MUPDATE
}

extern "C" void kernel_launch(void* const* d_in, const int* in_sizes, int n_in,
                              void* d_out, int out_size, void* d_ws, size_t ws_size,
                              hipStream_t stream) {
  const float* X = (const float*)d_in[0];
  const float* W = (const float*)d_in[1];
  float* Out = (float*)d_out;
  unsigned short* QKV = (unsigned short*)d_ws;

  const size_t QKV_E = (size_t)MROWS * NQKV;
  const size_t XB_E  = (size_t)MROWS * D_MODEL;
  const size_t WB_E  = (size_t)NQKV * D_MODEL;
  const size_t need_bf16 = (QKV_E + XB_E + WB_E) * 2;

  if (ws_size >= need_bf16) {
    unsigned short* Xb = QKV + QKV_E;
    unsigned short* Wb = Xb + XB_E;
    cvt_bf16<<<(XB_E + WB_E) / (256 * 8), 256, 0, stream>>>(X, W, Xb, Wb);
    gemm8<<<dim3(MROWS / 256, NQKV / 256), 512, 0, stream>>>(Xb, Wb, QKV);
  } else {
    qkv_gemm<<<dim3(MROWS / 128, NQKV / 128), 256, 0, stream>>>(X, W, QKV);
  }

  attn13<<<512, 512, 0, stream>>>(QKV, Out);
}